// Round 1
// baseline (98.765 us; speedup 1.0000x reference)
//
#include <hip/hip_runtime.h>

#define PI_F 3.14159265358979323846f

__device__ __forceinline__ float2 cmul(float2 a, float2 b) {
    return make_float2(fmaf(a.x, b.x, -(a.y * b.y)), fmaf(a.x, b.y, a.y * b.x));
}
__device__ __forceinline__ float2 cadd(float2 a, float2 b) {
    return make_float2(a.x + b.x, a.y + b.y);
}

// tanh via exp(-2|x|) — safe for large |x| (no inf/inf), accuracy ~1e-7.
__device__ __forceinline__ float tanh_fast(float x) {
    float ax = fabsf(x);
    float e = __expf(-2.0f * ax);
    float t = (1.0f - e) / (1.0f + e);
    return copysignf(t, x);
}

// Apply 2x2 complex gate U to qubit with bit-position BP (qubit q -> BP = 3-q).
template <int BP>
__device__ __forceinline__ void apply_gate(float2 st[16], float2 u00, float2 u01,
                                           float2 u10, float2 u11) {
#pragma unroll
    for (int i = 0; i < 8; i++) {
        const int lo = ((i >> BP) << (BP + 1)) | (i & ((1 << BP) - 1));
        const int hi = lo | (1 << BP);
        float2 a = st[lo], b = st[hi];
        st[lo] = cadd(cmul(u00, a), cmul(u01, b));
        st[hi] = cadd(cmul(u10, a), cmul(u11, b));
    }
}

// CNOT: control bit CB, target bit TB. Pure register permutation (free).
template <int CB, int TB>
__device__ __forceinline__ void cnot(float2 st[16]) {
#pragma unroll
    for (int i = 0; i < 16; i++) {
        if ((i & (1 << CB)) && !(i & (1 << TB))) {
            float2 t = st[i];
            st[i] = st[i | (1 << TB)];
            st[i | (1 << TB)] = t;
        }
    }
}

__global__ __launch_bounds__(256) void qlayer_kernel(const float* __restrict__ x,
                                                     const float* __restrict__ qw,
                                                     float* __restrict__ out, int B) {
    // 12 shared Rot matrices: Ug[l*4+q][n*2+o]
    __shared__ float2 Ug[12][4];
    const int tid = threadIdx.x;
    if (tid < 12) {
        const float phi = qw[tid * 3 + 0];
        const float th  = qw[tid * 3 + 1];
        const float om  = qw[tid * 3 + 2];
        // Rot = RZ(om) @ RY(th) @ RZ(phi):
        // u00 = cos(th/2) e^{-i(phi+om)/2}; u01 = -sin(th/2) e^{+i(phi-om)/2}
        // u10 = sin(th/2) e^{-i(phi-om)/2}; u11 =  cos(th/2) e^{+i(phi+om)/2}
        float s, c;   __sincosf(0.5f * th, &s, &c);
        float sa, ca; __sincosf(0.5f * (phi + om), &sa, &ca);
        float sb, cb; __sincosf(0.5f * (phi - om), &sb, &cb);
        Ug[tid][0] = make_float2(c * ca, -c * sa);
        Ug[tid][1] = make_float2(-s * cb, -s * sb);
        Ug[tid][2] = make_float2(s * cb, -s * sb);
        Ug[tid][3] = make_float2(c * ca, c * sa);
    }
    __syncthreads();

    const int b = blockIdx.x * 256 + tid;
    if (b >= B) return;

    const float4 xv = reinterpret_cast<const float4*>(x)[b];
    const float xs[4] = {xv.x, xv.y, xv.z, xv.w};

    // Encoded per-qubit vectors: v_q = (cos(xn) e^{-i xn/2}, sin(xn) e^{+i xn/2})
    float2 v[4][2];
#pragma unroll
    for (int q = 0; q < 4; q++) {
        const float xn = tanh_fast(xs[q]) * PI_F;
        float s, c;   __sincosf(xn, &s, &c);
        float sh, ch; __sincosf(0.5f * xn, &sh, &ch);
        v[q][0] = make_float2(c * ch, -c * sh);
        v[q][1] = make_float2(s * ch, s * sh);
    }

    // Merge layer-0 Rot gates into the (still product) state: v'_q = U_{0,q} v_q
#pragma unroll
    for (int q = 0; q < 4; q++) {
        const float2 u00 = Ug[q][0], u01 = Ug[q][1], u10 = Ug[q][2], u11 = Ug[q][3];
        const float2 a = v[q][0], bb = v[q][1];
        v[q][0] = cadd(cmul(u00, a), cmul(u01, bb));
        v[q][1] = cadd(cmul(u10, a), cmul(u11, bb));
    }

    // Outer product: st[i0*8+i1*4+i2*2+i3] = v0[i0] v1[i1] v2[i2] v3[i3]
    float2 st[16];
#pragma unroll
    for (int i = 0; i < 16; i++) {
        const float2 t01 = cmul(v[0][(i >> 3) & 1], v[1][(i >> 2) & 1]);
        const float2 t23 = cmul(v[2][(i >> 1) & 1], v[3][i & 1]);
        st[i] = cmul(t01, t23);
    }

    // Layer-0 CNOT ring: (0->1),(1->2),(2->3),(3->0); qubit q is bit 3-q.
    cnot<3, 2>(st); cnot<2, 1>(st); cnot<1, 0>(st); cnot<0, 3>(st);

    // Layers 1..2: Rot on each qubit, then CNOT ring.
#pragma unroll
    for (int l = 1; l < 3; l++) {
        apply_gate<3>(st, Ug[l * 4 + 0][0], Ug[l * 4 + 0][1], Ug[l * 4 + 0][2], Ug[l * 4 + 0][3]);
        apply_gate<2>(st, Ug[l * 4 + 1][0], Ug[l * 4 + 1][1], Ug[l * 4 + 1][2], Ug[l * 4 + 1][3]);
        apply_gate<1>(st, Ug[l * 4 + 2][0], Ug[l * 4 + 2][1], Ug[l * 4 + 2][2], Ug[l * 4 + 2][3]);
        apply_gate<0>(st, Ug[l * 4 + 3][0], Ug[l * 4 + 3][1], Ug[l * 4 + 3][2], Ug[l * 4 + 3][3]);
        cnot<3, 2>(st); cnot<2, 1>(st); cnot<1, 0>(st); cnot<0, 3>(st);
    }

    // <Z_q> = sum_i (+/-) |st[i]|^2, sign from bit (3-q) of i.
    float p[16];
#pragma unroll
    for (int i = 0; i < 16; i++) p[i] = fmaf(st[i].x, st[i].x, st[i].y * st[i].y);

    float4 ev = make_float4(0.f, 0.f, 0.f, 0.f);
#pragma unroll
    for (int i = 0; i < 16; i++) {
        ev.x += (i & 8) ? -p[i] : p[i];
        ev.y += (i & 4) ? -p[i] : p[i];
        ev.z += (i & 2) ? -p[i] : p[i];
        ev.w += (i & 1) ? -p[i] : p[i];
    }
    reinterpret_cast<float4*>(out)[b] = ev;
}

extern "C" void kernel_launch(void* const* d_in, const int* in_sizes, int n_in,
                              void* d_out, int out_size, void* d_ws, size_t ws_size,
                              hipStream_t stream) {
    const float* x  = (const float*)d_in[0];
    const float* qw = (const float*)d_in[1];
    float* out = (float*)d_out;
    const int B = in_sizes[0] / 4;
    const int blocks = (B + 255) / 256;
    qlayer_kernel<<<blocks, 256, 0, stream>>>(x, qw, out, B);
}

// Round 3
// 96.652 us; speedup vs baseline: 1.0219x; 1.0219x over previous
//
#include <hip/hip_runtime.h>

#define PI_F 3.14159265358979323846f

// u*a + w*b (complex), fully fma-chained: 4 ops per component.
__device__ __forceinline__ float2 cmadd2(float2 u, float2 a, float2 w, float2 b) {
    float re = fmaf(u.x, a.x, fmaf(-u.y, a.y, fmaf(w.x, b.x, -(w.y * b.y))));
    float im = fmaf(u.x, a.y, fmaf(u.y, a.x, fmaf(w.x, b.y, w.y * b.x)));
    return make_float2(re, im);
}
__device__ __forceinline__ float2 cmul(float2 a, float2 b) {
    return make_float2(fmaf(a.x, b.x, -(a.y * b.y)), fmaf(a.x, b.y, a.y * b.x));
}

// Apply 2x2 complex gate U to qubit with bit-position BP (qubit q -> BP = 3-q).
template <int BP>
__device__ __forceinline__ void apply_gate(float2 st[16], float2 u00, float2 u01,
                                           float2 u10, float2 u11) {
#pragma unroll
    for (int i = 0; i < 8; i++) {
        const int lo = ((i >> BP) << (BP + 1)) | (i & ((1 << BP) - 1));
        const int hi = lo | (1 << BP);
        float2 a = st[lo], b = st[hi];
        st[lo] = cmadd2(u00, a, u01, b);
        st[hi] = cmadd2(u10, a, u11, b);
    }
}

// CNOT: control bit CB, target bit TB. Pure register permutation (free).
template <int CB, int TB>
__device__ __forceinline__ void cnot(float2 st[16]) {
#pragma unroll
    for (int i = 0; i < 16; i++) {
        if ((i & (1 << CB)) && !(i & (1 << TB))) {
            float2 t = st[i];
            st[i] = st[i | (1 << TB)];
            st[i | (1 << TB)] = t;
        }
    }
}

__global__ __launch_bounds__(256) void qlayer_kernel(const float* __restrict__ x,
                                                     const float* __restrict__ qw,
                                                     float* __restrict__ out, int B) {
    // 12 shared Rot matrices, each as two float4: [u00.re u00.im u01.re u01.im][u10 u11]
    __shared__ float4 Ug[12][2];
    const int tid = threadIdx.x;
    if (tid < 12) {
        const float phi = qw[tid * 3 + 0];
        const float th  = qw[tid * 3 + 1];
        const float om  = qw[tid * 3 + 2];
        // Rot = RZ(om) @ RY(th) @ RZ(phi):
        // u00 = cos(th/2) e^{-i(phi+om)/2}; u01 = -sin(th/2) e^{+i(phi-om)/2}
        // u10 = sin(th/2) e^{-i(phi-om)/2}; u11 =  cos(th/2) e^{+i(phi+om)/2}
        float s, c;   __sincosf(0.5f * th, &s, &c);
        float sa, ca; __sincosf(0.5f * (phi + om), &sa, &ca);
        float sb, cb; __sincosf(0.5f * (phi - om), &sb, &cb);
        Ug[tid][0] = make_float4(c * ca, -c * sa, -s * cb, -s * sb);
        Ug[tid][1] = make_float4(s * cb, -s * sb, c * ca, c * sa);
    }
    __syncthreads();

    const int b = blockIdx.x * 256 + tid;
    if (b >= B) return;

    const float4 xv = reinterpret_cast<const float4*>(x)[b];
    const float xs[4] = {xv.x, xv.y, xv.z, xv.w};

    // Encoded per-qubit vectors: v_q = (cos(xn) e^{-i xn/2}, sin(xn) e^{+i xn/2}),
    // xn = pi * tanh(x_q). v_sin_f32/v_cos_f32 take REVOLUTIONS: sin(pi*t/2)=v_sin(t/4),
    // so no range reduction needed (t in (-1,1)). Full angle via double-angle.
    float2 v[4][2];
#pragma unroll
    for (int q = 0; q < 4; q++) {
        const float xq = xs[q];
        const float ax = fabsf(xq);
        // exp(-2|x|) = 2^(-2*log2(e)*|x|); v_exp_f32 computes 2^x.
        const float e  = __builtin_amdgcn_exp2f(ax * -2.8853900817779268f);
        const float r  = __builtin_amdgcn_rcpf(1.0f + e);
        const float t  = copysignf((1.0f - e) * r, xq);                     // tanh(x)
        const float sh = __builtin_amdgcn_sinf(t * 0.25f);                  // sin(pi t/2)
        const float ch = __builtin_amdgcn_cosf(t * 0.25f);                  // cos(pi t/2)
        const float s  = 2.0f * sh * ch;                                    // sin(pi t)
        const float c  = fmaf(-2.0f * sh, sh, 1.0f);                        // cos(pi t)
        v[q][0] = make_float2(c * ch, -(c * sh));
        v[q][1] = make_float2(s * ch, s * sh);
    }

    // Merge layer-0 Rot gates into the (still product) state: v'_q = U_{0,q} v_q
#pragma unroll
    for (int q = 0; q < 4; q++) {
        const float4 A = Ug[q][0], Bq = Ug[q][1];
        const float2 u00 = make_float2(A.x, A.y),  u01 = make_float2(A.z, A.w);
        const float2 u10 = make_float2(Bq.x, Bq.y), u11 = make_float2(Bq.z, Bq.w);
        const float2 a = v[q][0], bb = v[q][1];
        v[q][0] = cmadd2(u00, a, u01, bb);
        v[q][1] = cmadd2(u10, a, u11, bb);
    }

    // Outer product with explicit CSE: st[(i01<<2)|i23] = t01[i01]*t23[i23]
    float2 t01[4], t23[4];
#pragma unroll
    for (int i = 0; i < 4; i++) {
        t01[i] = cmul(v[0][(i >> 1) & 1], v[1][i & 1]);
        t23[i] = cmul(v[2][(i >> 1) & 1], v[3][i & 1]);
    }
    float2 st[16];
#pragma unroll
    for (int i = 0; i < 16; i++) st[i] = cmul(t01[i >> 2], t23[i & 3]);

    // Layer-0 CNOT ring: (0->1),(1->2),(2->3),(3->0); qubit q is bit 3-q.
    cnot<3, 2>(st); cnot<2, 1>(st); cnot<1, 0>(st); cnot<0, 3>(st);

    // Layers 1..2: Rot on each qubit, then CNOT ring.
#pragma unroll
    for (int l = 1; l < 3; l++) {
#pragma unroll
        for (int q = 0; q < 4; q++) {
            const int g = l * 4 + q;
            const float4 A = Ug[g][0], Bq = Ug[g][1];
            const float2 u00 = make_float2(A.x, A.y),  u01 = make_float2(A.z, A.w);
            const float2 u10 = make_float2(Bq.x, Bq.y), u11 = make_float2(Bq.z, Bq.w);
            switch (q) {
                case 0: apply_gate<3>(st, u00, u01, u10, u11); break;
                case 1: apply_gate<2>(st, u00, u01, u10, u11); break;
                case 2: apply_gate<1>(st, u00, u01, u10, u11); break;
                case 3: apply_gate<0>(st, u00, u01, u10, u11); break;
            }
        }
        cnot<3, 2>(st); cnot<2, 1>(st); cnot<1, 0>(st); cnot<0, 3>(st);
    }

    // Readout. State is normalized (unitary circuit) => <Z_q> = 1 - 2*sum_{bit_q=1} p.
    float p[16];
#pragma unroll
    for (int i = 0; i < 16; i++) p[i] = fmaf(st[i].x, st[i].x, st[i].y * st[i].y);

    float pr[8];
#pragma unroll
    for (int j = 0; j < 8; j++) pr[j] = p[2 * j] + p[2 * j + 1];

    const float s3 = (pr[4] + pr[5]) + (pr[6] + pr[7]);                    // bit3=1
    const float s2 = (pr[2] + pr[3]) + (pr[6] + pr[7]);                    // bit2=1
    const float s1 = (pr[1] + pr[3]) + (pr[5] + pr[7]);                    // bit1=1
    const float s0 = ((p[1] + p[3]) + (p[5] + p[7])) +
                     ((p[9] + p[11]) + (p[13] + p[15]));                   // bit0=1

    float4 ev;
    ev.x = fmaf(-2.0f, s3, 1.0f);
    ev.y = fmaf(-2.0f, s2, 1.0f);
    ev.z = fmaf(-2.0f, s1, 1.0f);
    ev.w = fmaf(-2.0f, s0, 1.0f);
    reinterpret_cast<float4*>(out)[b] = ev;
}

extern "C" void kernel_launch(void* const* d_in, const int* in_sizes, int n_in,
                              void* d_out, int out_size, void* d_ws, size_t ws_size,
                              hipStream_t stream) {
    const float* x  = (const float*)d_in[0];
    const float* qw = (const float*)d_in[1];
    float* out = (float*)d_out;
    const int B = in_sizes[0] / 4;
    const int blocks = (B + 255) / 256;
    qlayer_kernel<<<blocks, 256, 0, stream>>>(x, qw, out, B);
}

// Round 4
// 95.463 us; speedup vs baseline: 1.0346x; 1.0125x over previous
//
#include <hip/hip_runtime.h>

// Packed-SoA complex amplitude: .re/.im each hold {sample A, sample B}.
// All gate math is element-wise over the sample pair -> v_pk_fma_f32.
struct P { float2 re, im; };

__device__ __forceinline__ float2 f2(float x, float y) { return make_float2(x, y); }
__device__ __forceinline__ float2 splat(float s) { return make_float2(s, s); }
__device__ __forceinline__ float2 add2(float2 a, float2 b) { return f2(a.x + b.x, a.y + b.y); }
__device__ __forceinline__ float2 mul2(float2 a, float2 b) { return f2(a.x * b.x, a.y * b.y); }
__device__ __forceinline__ float2 neg2(float2 a) { return f2(-a.x, -a.y); }
__device__ __forceinline__ float2 fma2(float2 a, float2 b, float2 c) {
    return f2(fmaf(a.x, b.x, c.x), fmaf(a.y, b.y, c.y));
}

// r = u*a + w*b where u,w are complex SCALARS (shared gate entries), a,b packed amps.
__device__ __forceinline__ P cmadd2p(float2 u, float2 w, const P& a, const P& b) {
    P r;
    r.re = fma2(splat(u.x), a.re,
           fma2(splat(-u.y), a.im,
           fma2(splat(w.x), b.re, mul2(splat(-w.y), b.im))));
    r.im = fma2(splat(u.x), a.im,
           fma2(splat(u.y), a.re,
           fma2(splat(w.x), b.im, mul2(splat(w.y), b.re))));
    return r;
}

// Packed complex multiply (both operands packed).
__device__ __forceinline__ P cmulp(const P& a, const P& b) {
    P r;
    r.re = fma2(a.re, b.re, mul2(neg2(a.im), b.im));
    r.im = fma2(a.re, b.im, mul2(a.im, b.re));
    return r;
}

// Apply 2x2 complex gate (A4=[u00.re u00.im u01.re u01.im], B4=[u10 u11]) to bit BP.
template <int BP>
__device__ __forceinline__ void apply_gate(P st[16], float4 A4, float4 B4) {
    const float2 u00 = f2(A4.x, A4.y), u01 = f2(A4.z, A4.w);
    const float2 u10 = f2(B4.x, B4.y), u11 = f2(B4.z, B4.w);
#pragma unroll
    for (int i = 0; i < 8; i++) {
        const int lo = ((i >> BP) << (BP + 1)) | (i & ((1 << BP) - 1));
        const int hi = lo | (1 << BP);
        const P a = st[lo], b = st[hi];
        st[lo] = cmadd2p(u00, u01, a, b);
        st[hi] = cmadd2p(u10, u11, a, b);
    }
}

// CNOT: pure register permutation (free).
template <int CB, int TB>
__device__ __forceinline__ void cnot(P st[16]) {
#pragma unroll
    for (int i = 0; i < 16; i++) {
        if ((i & (1 << CB)) && !(i & (1 << TB))) {
            P t = st[i];
            st[i] = st[i | (1 << TB)];
            st[i | (1 << TB)] = t;
        }
    }
}

struct Enc { float r0, i0, r1, i1; };
// v_q = (cos(xn) e^{-i xn/2}, sin(xn) e^{+i xn/2}), xn = pi*tanh(x).
// HW v_sin/v_cos take REVOLUTIONS: sin(pi t/2) = v_sin(t/4), t in (-1,1) -> no range reduction.
__device__ __forceinline__ Enc encode(float xq) {
    const float ax = fabsf(xq);
    const float e  = __builtin_amdgcn_exp2f(ax * -2.8853900817779268f);  // exp(-2|x|)
    const float r  = __builtin_amdgcn_rcpf(1.0f + e);
    const float t  = copysignf((1.0f - e) * r, xq);                       // tanh(x)
    const float sh = __builtin_amdgcn_sinf(t * 0.25f);                    // sin(pi t/2)
    const float ch = __builtin_amdgcn_cosf(t * 0.25f);                    // cos(pi t/2)
    const float s  = 2.0f * sh * ch;                                      // sin(pi t)
    const float c  = fmaf(-2.0f * sh, sh, 1.0f);                          // cos(pi t)
    return {c * ch, -(c * sh), s * ch, s * sh};
}

__global__ __launch_bounds__(256) void qlayer_kernel(const float* __restrict__ x,
                                                     const float* __restrict__ qw,
                                                     float* __restrict__ out, int B) {
    __shared__ float4 Ug[12][2];
    const int tid = threadIdx.x;
    if (tid < 12) {
        const float phi = qw[tid * 3 + 0];
        const float th  = qw[tid * 3 + 1];
        const float om  = qw[tid * 3 + 2];
        // Rot = RZ(om) RY(th) RZ(phi)
        float s, c;   __sincosf(0.5f * th, &s, &c);
        float sa, ca; __sincosf(0.5f * (phi + om), &sa, &ca);
        float sb, cb; __sincosf(0.5f * (phi - om), &sb, &cb);
        Ug[tid][0] = make_float4(c * ca, -c * sa, -s * cb, -s * sb);
        Ug[tid][1] = make_float4(s * cb, -s * sb, c * ca, c * sa);
    }
    __syncthreads();

    const int bA = blockIdx.x * 512 + tid;       // sample A
    if (bA >= B) return;
    const int bB0 = bA + 256;                    // sample B (may be OOB on tail)
    const bool hasB = bB0 < B;
    const int bB = hasB ? bB0 : bA;

    const float4 xA = reinterpret_cast<const float4*>(x)[bA];
    const float4 xB = reinterpret_cast<const float4*>(x)[bB];
    const float xsA[4] = {xA.x, xA.y, xA.z, xA.w};
    const float xsB[4] = {xB.x, xB.y, xB.z, xB.w};

    // Encode + merge layer-0 Rot into the per-qubit 2-vectors (still product state).
    P v[4][2];
#pragma unroll
    for (int q = 0; q < 4; q++) {
        const Enc eA = encode(xsA[q]);
        const Enc eB = encode(xsB[q]);
        P a; a.re = f2(eA.r0, eB.r0); a.im = f2(eA.i0, eB.i0);
        P b; b.re = f2(eA.r1, eB.r1); b.im = f2(eA.i1, eB.i1);
        const float4 A4 = Ug[q][0], B4 = Ug[q][1];
        v[q][0] = cmadd2p(f2(A4.x, A4.y), f2(A4.z, A4.w), a, b);
        v[q][1] = cmadd2p(f2(B4.x, B4.y), f2(B4.z, B4.w), a, b);
    }

    // Outer product: st[(i01<<2)|i23] = t01[i01] * t23[i23]
    P t01[4], t23[4];
#pragma unroll
    for (int i = 0; i < 4; i++) {
        t01[i] = cmulp(v[0][(i >> 1) & 1], v[1][i & 1]);
        t23[i] = cmulp(v[2][(i >> 1) & 1], v[3][i & 1]);
    }
    P st[16];
#pragma unroll
    for (int i = 0; i < 16; i++) st[i] = cmulp(t01[i >> 2], t23[i & 3]);

    // Layer-0 CNOT ring (qubit q -> bit 3-q).
    cnot<3, 2>(st); cnot<2, 1>(st); cnot<1, 0>(st); cnot<0, 3>(st);

    // Layer 1
    apply_gate<3>(st, Ug[4][0], Ug[4][1]);
    apply_gate<2>(st, Ug[5][0], Ug[5][1]);
    apply_gate<1>(st, Ug[6][0], Ug[6][1]);
    apply_gate<0>(st, Ug[7][0], Ug[7][1]);
    cnot<3, 2>(st); cnot<2, 1>(st); cnot<1, 0>(st); cnot<0, 3>(st);
    // Layer 2
    apply_gate<3>(st, Ug[8][0], Ug[8][1]);
    apply_gate<2>(st, Ug[9][0], Ug[9][1]);
    apply_gate<1>(st, Ug[10][0], Ug[10][1]);
    apply_gate<0>(st, Ug[11][0], Ug[11][1]);
    cnot<3, 2>(st); cnot<2, 1>(st); cnot<1, 0>(st); cnot<0, 3>(st);

    // Readout: normalized state => <Z_q> = 1 - 2*sum_{bit(3-q)=1} |amp|^2. All packed.
    float2 p[16];
#pragma unroll
    for (int i = 0; i < 16; i++) p[i] = fma2(st[i].re, st[i].re, mul2(st[i].im, st[i].im));

    float2 pr[8];
#pragma unroll
    for (int j = 0; j < 8; j++) pr[j] = add2(p[2 * j], p[2 * j + 1]);

    const float2 s3 = add2(add2(pr[4], pr[5]), add2(pr[6], pr[7]));
    const float2 s2 = add2(add2(pr[2], pr[3]), add2(pr[6], pr[7]));
    const float2 s1 = add2(add2(pr[1], pr[3]), add2(pr[5], pr[7]));
    const float2 s0 = add2(add2(add2(p[1], p[3]), add2(p[5], p[7])),
                           add2(add2(p[9], p[11]), add2(p[13], p[15])));

    float4 evA, evB;
    evA.x = fmaf(-2.0f, s3.x, 1.0f); evB.x = fmaf(-2.0f, s3.y, 1.0f);
    evA.y = fmaf(-2.0f, s2.x, 1.0f); evB.y = fmaf(-2.0f, s2.y, 1.0f);
    evA.z = fmaf(-2.0f, s1.x, 1.0f); evB.z = fmaf(-2.0f, s1.y, 1.0f);
    evA.w = fmaf(-2.0f, s0.x, 1.0f); evB.w = fmaf(-2.0f, s0.y, 1.0f);

    reinterpret_cast<float4*>(out)[bA] = evA;
    if (hasB) reinterpret_cast<float4*>(out)[bB0] = evB;
}

extern "C" void kernel_launch(void* const* d_in, const int* in_sizes, int n_in,
                              void* d_out, int out_size, void* d_ws, size_t ws_size,
                              hipStream_t stream) {
    const float* x  = (const float*)d_in[0];
    const float* qw = (const float*)d_in[1];
    float* out = (float*)d_out;
    const int B = in_sizes[0] / 4;
    const int blocks = (B + 511) / 512;   // 2 samples per thread
    qlayer_kernel<<<blocks, 256, 0, stream>>>(x, qw, out, B);
}